// Round 6
// baseline (236.323 us; speedup 1.0000x reference)
//
#include <hip/hip_runtime.h>
#include <hip/hip_fp16.h>

// SpatialTransform: fused meshgrid + flow displacement + bilinear grid_sample
// (align_corners=True, padding_mode='border'). B=16, C=4, H=W=512, fp32.
// d_out = [ sample_grid (B*H*W*2 floats) | warped (B*C*H*W floats) ]
//
// R9 = R8 resubmitted verbatim (R8 bench was an infra failure: container
// died twice; no counters). Rationale from R8:
//  Pass2 model: per-lane divergent-request cost (~4cy/req in TA/TCP):
//  8 req/thread * 64 waves/CU * 64 lanes * 4cy ~= 55us ~= measured 60.
//  R7's -37.5% line reduction gave only -12% -> requests, not lines, bind.
//  2 reqs/sample is structural (32B/sample, 16B/lane max) -> pass2 is near
//  its wall; FROZEN as control.
//  Pass1 fix: R6/R7's LDS staging has a 32-way bank conflict (S[x][rb]
//  uint2, lane stride 64B -> all lanes on banks {0,16} for each
//  ds_write_b64 x4, 8-way on reads). Remove LDS entirely: direct 8B
//  stores at 16B stride (half-line pattern R6 PROVED merges in L2 with no
//  fill/no amplification). No barrier, no conflicts, wave-uniform rb.
//  Kept: y-paired E/O copies, 4px/thread, nt img/flow loads, nt grid +
//  warped stores (lane-contiguous), XCD slab swizzle (pass1 fwd, pass2 rev).

#define HW    512
#define BATCH 16
#define CH     4
#define HWHW  (HW * HW)

typedef float fvec4 __attribute__((ext_vector_type(4)));
typedef float fvec2 __attribute__((ext_vector_type(2)));

union H4 { uint2 u; __half2 h[2]; };   // one pixel: 4 channels fp16
union Q  { uint4 u; __half2 h[4]; };   // one entry: 2 pixels x 4 channels fp16

// ---------------------------------------------------------------------------
// Pass 1: [B,C,H,W] fp32 -> two y-paired fp16 HWC copies, direct stores.
// E[rp][x] = {px(x,2rp) lo, px(x,2rp+1) hi}
// O[yp][x] = {px(x,2yp+1) lo, px(x,2yp+2) hi}; O[255].hi = row 511 (clamp).
// Block = one row-pair (2 rows); thread (rb,lane) owns 4 px of row 2rp+rb.
__global__ __launch_bounds__(256) void transpose_fp16_dual(
    const fvec4* __restrict__ img4,
    uint4* __restrict__ E,
    uint4* __restrict__ O)
{
    // 4096 blocks; xcd = j&7 owns contiguous slabs (forward order).
    const int j    = blockIdx.x;
    const int xcd  = j & 7;
    const int i    = j >> 3;                        // 0..511
    const int slab = ((i >> 7) << 3) | xcd;         // 0..31
    const int rp   = (slab << 7) | (i & 127);       // global row-pair 0..4095
    const int rb   = (int)threadIdx.x >> 7;         // row within pair (0/1)
    const int r    = (rp << 1) | rb;                // global row 0..8191
    const int lane = (int)threadIdx.x & 127;
    const int b    = r >> 9;
    const int y    = r & (HW - 1);
    const int x    = lane << 2;                     // 0,4,...,508

    const int q = (y * HW + x) >> 2;                // quad index within plane
    const fvec4* ib = img4 + (size_t)b * CH * (HWHW / 4) + q;
    const fvec4 c0 = __builtin_nontemporal_load(ib + 0 * (HWHW / 4));
    const fvec4 c1 = __builtin_nontemporal_load(ib + 1 * (HWHW / 4));
    const fvec4 c2 = __builtin_nontemporal_load(ib + 2 * (HWHW / 4));
    const fvec4 c3 = __builtin_nontemporal_load(ib + 3 * (HWHW / 4));

    H4 v0, v1, v2, v3;                              // pixels x..x+3 of row r
    v0.h[0] = __floats2half2_rn(c0.x, c1.x); v0.h[1] = __floats2half2_rn(c2.x, c3.x);
    v1.h[0] = __floats2half2_rn(c0.y, c1.y); v1.h[1] = __floats2half2_rn(c2.y, c3.y);
    v2.h[0] = __floats2half2_rn(c0.z, c1.z); v2.h[1] = __floats2half2_rn(c2.z, c3.z);
    v3.h[0] = __floats2half2_rn(c0.w, c1.w); v3.h[1] = __floats2half2_rn(c2.w, c3.w);

    const int rpl = rp & 255;                       // row-pair within image
    const int xi  = x << 1;                         // uint2 index of entry x

    // E: this row's half of entries x..x+3 (8B stores, 16B stride; L2 merges)
    uint2* Ep = (uint2*)(E + ((size_t)rp << 9));
    Ep[xi + 0 + rb] = v0.u;
    Ep[xi + 2 + rb] = v1.u;
    Ep[xi + 4 + rb] = v2.u;
    Ep[xi + 6 + rb] = v3.u;

    if (rb == 0) {                                  // row 2rp -> O[rp-1].hi
        if (rpl != 0) {
            uint2* Oh = (uint2*)(O + ((size_t)(rp - 1) << 9));
            Oh[xi + 1] = v0.u;
            Oh[xi + 3] = v1.u;
            Oh[xi + 5] = v2.u;
            Oh[xi + 7] = v3.u;
        }
    } else {                                        // row 2rp+1 -> O[rp].lo
        uint2* Ol = (uint2*)(O + ((size_t)rp << 9));
        Ol[xi + 0] = v0.u;
        Ol[xi + 2] = v1.u;
        Ol[xi + 4] = v2.u;
        Ol[xi + 6] = v3.u;
        if (rpl == 255) {                           // clamp: row 512 -> 511
            Ol[xi + 1] = v0.u;
            Ol[xi + 3] = v1.u;
            Ol[xi + 5] = v2.u;
            Ol[xi + 7] = v3.u;
        }
    }
}

// ---------------------------------------------------------------------------
// Bilinear addressing into the y-paired copies.
__device__ __forceinline__ void addrEO(const uint4* __restrict__ E,
                                       const uint4* __restrict__ O,
                                       float gx, float gy,
                                       const uint4** p0, int* dx,
                                       float* wx, float* wy)
{
    float xs = fminf(fmaxf((gx + 1.0f) * 0.5f * 511.0f, 0.0f), 511.0f);
    float ys = fminf(fmaxf((gy + 1.0f) * 0.5f * 511.0f, 0.0f), 511.0f);
    const float x0f = floorf(xs);
    const float y0f = floorf(ys);
    *wx = xs - x0f;
    *wy = ys - y0f;
    const int x0 = (int)x0f;
    const int y0 = (int)y0f;
    const uint4* base = (y0 & 1) ? O : E;
    *p0 = base + (((size_t)(y0 >> 1)) << 9) + x0;
    *dx = (x0 < HW - 1) ? 1 : 0;                    // border clamp in x
}

// c0 = column x0: {v00 (h[0..1]), v10 (h[2..3])}; c1 = column x1: {v01, v11}.
__device__ __forceinline__ float4 blendEO(Q c0, Q c1, float wx, float wy)
{
    const float w00 = (1.0f - wx) * (1.0f - wy);
    const float w01 = wx * (1.0f - wy);
    const float w10 = (1.0f - wx) * wy;
    const float w11 = wx * wy;
    float4 o;
    o.x = w00 * __low2float (c0.h[0]) + w01 * __low2float (c1.h[0])
        + w10 * __low2float (c0.h[2]) + w11 * __low2float (c1.h[2]);
    o.y = w00 * __high2float(c0.h[0]) + w01 * __high2float(c1.h[0])
        + w10 * __high2float(c0.h[2]) + w11 * __high2float(c1.h[2]);
    o.z = w00 * __low2float (c0.h[1]) + w01 * __low2float (c1.h[1])
        + w10 * __low2float (c0.h[3]) + w11 * __low2float (c1.h[3]);
    o.w = w00 * __high2float(c0.h[1]) + w01 * __high2float(c1.h[1])
        + w10 * __high2float(c0.h[3]) + w11 * __high2float(c1.h[3]);
    return o;
}

// Pass 2 (UNCHANGED from R7 — control): 2 rows/block, thread owns pixel-pairs
// l and l+128 of its row; slab-swizzled to XCDs in REVERSE order.
__global__ __launch_bounds__(256) void spatial_transform_fp16(
    const uint4* __restrict__ E,
    const uint4* __restrict__ O,
    const fvec4* __restrict__ flow4, // [B*H*W/2]: (fh0,fw0,fh1,fw1)
    fvec4* __restrict__ grid4,       // [B*H*W/2]: (gx0,gy0,gx1,gy1)
    float* __restrict__ warped)      // [B,C,H,W]
{
    const int j    = blockIdx.x;                    // 0..4095
    const int xcd  = j & 7;
    const int i    = (j >> 3) ^ 511;                // REVERSED intra-XCD order
    const int slab = ((i >> 7) << 3) | xcd;         // 0..31
    const int rp   = (slab << 7) | (i & 127);       // row-pair 0..4095
    const int r    = (rp << 1) | ((int)threadIdx.x >> 7);  // global row
    const int l    = (int)threadIdx.x & 127;
    const int b    = r >> 9;
    const int y    = r & (HW - 1);

    const int rowq = r << 8;                        // first pair-idx of row
    const fvec4 fA = __builtin_nontemporal_load(flow4 + rowq + l);
    const fvec4 fB = __builtin_nontemporal_load(flow4 + rowq + l + 128);

    const float scale = 2.0f / 511.0f;
    const float by = fmaf((float)y, scale, -1.0f);
    const int  xA = l << 1;                         // pixels xA, xA+1
    const int  xB = xA + 256;                       // pixels xB, xB+1
    const float gyA0 = by + fA.x;
    const float gxA0 = fmaf((float)(xA + 0), scale, -1.0f) + fA.y;
    const float gyA1 = by + fA.z;
    const float gxA1 = fmaf((float)(xA + 1), scale, -1.0f) + fA.w;
    const float gyB0 = by + fB.x;
    const float gxB0 = fmaf((float)(xB + 0), scale, -1.0f) + fB.y;
    const float gyB1 = by + fB.z;
    const float gxB1 = fmaf((float)(xB + 1), scale, -1.0f) + fB.w;

    const uint4* Eb = E + ((size_t)b << 17);        // 256*512 entries/image
    const uint4* Ob = O + ((size_t)b << 17);

    // Phase A: all addresses
    const uint4 *pA0, *pA1, *pB0, *pB1;
    int dA0, dA1, dB0, dB1;
    float wxA0, wyA0, wxA1, wyA1, wxB0, wyB0, wxB1, wyB1;
    addrEO(Eb, Ob, gxA0, gyA0, &pA0, &dA0, &wxA0, &wyA0);
    addrEO(Eb, Ob, gxA1, gyA1, &pA1, &dA1, &wxA1, &wyA1);
    addrEO(Eb, Ob, gxB0, gyB0, &pB0, &dB0, &wxB0, &wyB0);
    addrEO(Eb, Ob, gxB1, gyB1, &pB1, &dB1, &wxB1, &wyB1);

    // Phase B: 8 independent gathers in flight (pairs mostly share lines)
    Q a00, a01, a10, a11, b00, b01, b10, b11;
    a00.u = pA0[0]; a01.u = pA0[dA0];
    a10.u = pA1[0]; a11.u = pA1[dA1];
    b00.u = pB0[0]; b01.u = pB0[dB0];
    b10.u = pB1[0]; b11.u = pB1[dB1];

    // grid: nt + lane-contiguous (16B/lane, no amplification, no L2 pollution)
    fvec4 gA; gA.x = gxA0; gA.y = gyA0; gA.z = gxA1; gA.w = gyA1;
    fvec4 gB; gB.x = gxB0; gB.y = gyB0; gB.z = gxB1; gB.w = gyB1;
    __builtin_nontemporal_store(gA, grid4 + rowq + l);
    __builtin_nontemporal_store(gB, grid4 + rowq + l + 128);

    // Phase C: blend + transposed channel stores (8B/lane, lane-contiguous)
    const float4 s0 = blendEO(a00, a01, wxA0, wyA0);   // pixel xA
    const float4 s1 = blendEO(a10, a11, wxA1, wyA1);   // pixel xA+1
    const float4 s2 = blendEO(b00, b01, wxB0, wyB0);   // pixel xB
    const float4 s3 = blendEO(b10, b11, wxB1, wyB1);   // pixel xB+1

    fvec2* w2 = (fvec2*)(warped + (size_t)b * CH * HWHW + y * HW);
    fvec2 o0a; o0a.x = s0.x; o0a.y = s1.x;
    fvec2 o0b; o0b.x = s2.x; o0b.y = s3.x;
    fvec2 o1a; o1a.x = s0.y; o1a.y = s1.y;
    fvec2 o1b; o1b.x = s2.y; o1b.y = s3.y;
    fvec2 o2a; o2a.x = s0.z; o2a.y = s1.z;
    fvec2 o2b; o2b.x = s2.z; o2b.y = s3.z;
    fvec2 o3a; o3a.x = s0.w; o3a.y = s1.w;
    fvec2 o3b; o3b.x = s2.w; o3b.y = s3.w;
    __builtin_nontemporal_store(o0a, w2 + 0 * (HWHW / 2) + l);
    __builtin_nontemporal_store(o0b, w2 + 0 * (HWHW / 2) + l + 128);
    __builtin_nontemporal_store(o1a, w2 + 1 * (HWHW / 2) + l);
    __builtin_nontemporal_store(o1b, w2 + 1 * (HWHW / 2) + l + 128);
    __builtin_nontemporal_store(o2a, w2 + 2 * (HWHW / 2) + l);
    __builtin_nontemporal_store(o2b, w2 + 2 * (HWHW / 2) + l + 128);
    __builtin_nontemporal_store(o3a, w2 + 3 * (HWHW / 2) + l);
    __builtin_nontemporal_store(o3b, w2 + 3 * (HWHW / 2) + l + 128);
}

// ---------------------------------------------------------------------------
// Fallback (R0 path) if workspace is too small.
__global__ __launch_bounds__(256) void spatial_transform_chw(
    const float*  __restrict__ img,
    const float2* __restrict__ flow,
    float2*       __restrict__ grid_out,
    float*        __restrict__ warped)
{
    const int tid = blockIdx.x * blockDim.x + threadIdx.x;
    const int x = tid & (HW - 1);
    const int y = (tid >> 9) & (HW - 1);
    const int b = tid >> 18;

    const float2 f = flow[tid];
    const float scale = 2.0f / 511.0f;
    const float gy = fmaf((float)y, scale, -1.0f) + f.x;
    const float gx = fmaf((float)x, scale, -1.0f) + f.y;
    grid_out[tid] = make_float2(gx, gy);

    float xs = fminf(fmaxf((gx + 1.0f) * 0.5f * 511.0f, 0.0f), 511.0f);
    float ys = fminf(fmaxf((gy + 1.0f) * 0.5f * 511.0f, 0.0f), 511.0f);
    const float x0f = floorf(xs), y0f = floorf(ys);
    const float wx = xs - x0f, wy = ys - y0f;
    const int x0 = (int)x0f, y0 = (int)y0f;
    const int x1 = min(x0 + 1, HW - 1), y1 = min(y0 + 1, HW - 1);
    const float w00 = (1.0f - wx) * (1.0f - wy), w01 = wx * (1.0f - wy);
    const float w10 = (1.0f - wx) * wy,          w11 = wx * wy;
    const int o00 = y0 * HW + x0, o01 = y0 * HW + x1;
    const int o10 = y1 * HW + x0, o11 = y1 * HW + x1;
    const float* ib = img    + (size_t)b * CH * HWHW;
    float*       wb = warped + (size_t)b * CH * HWHW + y * HW + x;
#pragma unroll
    for (int c = 0; c < CH; ++c) {
        const float* pc = ib + c * HWHW;
        wb[c * HWHW] = pc[o00] * w00 + pc[o01] * w01 + pc[o10] * w10 + pc[o11] * w11;
    }
}

extern "C" void kernel_launch(void* const* d_in, const int* in_sizes, int n_in,
                              void* d_out, int out_size, void* d_ws, size_t ws_size,
                              hipStream_t stream) {
    const float* img  = (const float*)d_in[0];
    const void*  flow = d_in[1];

    float* grid_out = (float*)d_out;                                  // B*H*W*2 floats
    float* warped   = (float*)d_out + (size_t)BATCH * HWHW * 2;       // B*C*H*W floats

    const int n_px = BATCH * HWHW;                       // 4,194,304 pixels
    const size_t copy_bytes = (size_t)n_px * 8;          // 32 MiB per copy
    const size_t need = 2 * copy_bytes;                  // 64 MiB (E + O)

    if (ws_size >= need) {
        uint4* Ec = (uint4*)d_ws;
        uint4* Oc = (uint4*)((char*)d_ws + copy_bytes);
        transpose_fp16_dual<<<(n_px / 4) / 256, 256, 0, stream>>>(
            (const fvec4*)img, Ec, Oc);
        spatial_transform_fp16<<<(n_px / 4) / 256, 256, 0, stream>>>(
            (const uint4*)Ec, (const uint4*)Oc,
            (const fvec4*)flow, (fvec4*)grid_out, warped);
    } else {
        spatial_transform_chw<<<n_px / 256, 256, 0, stream>>>(
            img, (const float2*)flow, (float2*)grid_out, warped);
    }
}

// Round 7
// 214.740 us; speedup vs baseline: 1.1005x; 1.1005x over previous
//
#include <hip/hip_runtime.h>
#include <hip/hip_fp16.h>

// SpatialTransform: fused meshgrid + flow displacement + bilinear grid_sample
// (align_corners=True, padding_mode='border'). B=16, C=4, H=W=512, fp32.
// d_out = [ sample_grid (B*H*W*2 floats) | warped (B*C*H*W floats) ]
//
// R10 (from R9 @ 236.3us, pass2 59.8us control-stable):
//  R9 post-mortem: de-LDS pass1 REGRESSED +21us. Its stores were 8B at
//  64B lane stride = every lane its own line = 8 instr x 64 divergent
//  TA requests -- the same per-lane request cost that bounds pass2's
//  gathers, self-inflicted. R7's LDS version beat it even with 32-way
//  LDS write conflicts (LDS conflict ~N/2.8 cy << 512 TA requests).
//  FIX: remap thread->data so no LDS and no divergence: one block per
//  row-pair, 512 threads, thread t owns E-entry x=t (pixel t of BOTH
//  rows). 8 coalesced scalar loads (4ch x 2rows, 4B/lane contiguous),
//  ONE full-line uint4 E store (16B lane stride), two 8B O-half stores
//  at 16B stride (pattern R6/R7 PROVED merges in L2, no fill). 11 VMEM
//  instr/thread, all coalesced, zero divergent requests, zero LDS.
//  Pass2 FROZEN (control): per-lane divergent-request wall ~60us
//  (2 req/sample structural at fp16: 32B/sample, 16B/req max).
//  Kept: y-paired E/O copies, nt img/flow loads, nt grid+warped stores,
//  XCD slab swizzle (pass1 fwd, pass2 rev).

#define HW    512
#define BATCH 16
#define CH     4
#define HWHW  (HW * HW)

typedef float fvec4 __attribute__((ext_vector_type(4)));
typedef float fvec2 __attribute__((ext_vector_type(2)));

union H4 { uint2 u; __half2 h[2]; };   // one pixel: 4 channels fp16
union Q  { uint4 u; __half2 h[4]; };   // one entry: 2 pixels x 4 channels fp16

// ---------------------------------------------------------------------------
// Pass 1: [B,C,H,W] fp32 -> two y-paired fp16 HWC copies, direct stores.
// E[rp][x] = {px(x,2rp) lo, px(x,2rp+1) hi}
// O[yp][x] = {px(x,2yp+1) lo, px(x,2yp+2) hi}; O[255].hi = row 511 (clamp).
// One block per row-pair; thread t owns pixel x=t of both rows.
__global__ __launch_bounds__(512) void transpose_fp16_pair(
    const float* __restrict__ img,
    uint4* __restrict__ E,
    uint4* __restrict__ O)
{
    // 4096 blocks; xcd = j&7 owns contiguous slabs (forward order).
    const int j    = blockIdx.x;
    const int xcd  = j & 7;
    const int i    = j >> 3;                        // 0..511
    const int slab = ((i >> 7) << 3) | xcd;         // 0..31
    const int rp   = (slab << 7) | (i & 127);       // global row-pair 0..4095
    const int x    = (int)threadIdx.x;              // entry / pixel x 0..511
    const int b    = rp >> 8;
    const int rpl  = rp & 255;                      // row-pair within image
    const int y0   = rpl << 1;                      // even row 0..510

    const float* ib = img + (size_t)b * CH * HWHW + y0 * HW + x;
    // 8 coalesced scalar loads: 4 channels x rows y0, y0+1.
    const float r0c0 = __builtin_nontemporal_load(ib + 0 * HWHW);
    const float r0c1 = __builtin_nontemporal_load(ib + 1 * HWHW);
    const float r0c2 = __builtin_nontemporal_load(ib + 2 * HWHW);
    const float r0c3 = __builtin_nontemporal_load(ib + 3 * HWHW);
    const float r1c0 = __builtin_nontemporal_load(ib + 0 * HWHW + HW);
    const float r1c1 = __builtin_nontemporal_load(ib + 1 * HWHW + HW);
    const float r1c2 = __builtin_nontemporal_load(ib + 2 * HWHW + HW);
    const float r1c3 = __builtin_nontemporal_load(ib + 3 * HWHW + HW);

    H4 v0, v1;                                      // rows y0, y0+1 @ pixel x
    v0.h[0] = __floats2half2_rn(r0c0, r0c1);
    v0.h[1] = __floats2half2_rn(r0c2, r0c3);
    v1.h[0] = __floats2half2_rn(r1c0, r1c1);
    v1.h[1] = __floats2half2_rn(r1c2, r1c3);

    // E entry x: full 16B store, 16B lane stride -> full-line coalesced.
    Q e; e.u.x = v0.u.x; e.u.y = v0.u.y; e.u.z = v1.u.x; e.u.w = v1.u.y;
    (E + ((size_t)rp << 9))[x] = e.u;

    // O halves: 8B stores at 16B stride (4 lanes/line, 50% coverage; L2
    // merges with the complementary half from the adjacent block - proven).
    uint2* Ol = (uint2*)(O + ((size_t)rp << 9));
    Ol[2 * x] = v1.u;                               // O[rp].lo = row y0+1
    if (rpl != 0) {
        uint2* Oh = (uint2*)(O + ((size_t)(rp - 1) << 9));
        Oh[2 * x + 1] = v0.u;                       // O[rp-1].hi = row y0
    }
    if (rpl == 255) {                               // clamp: row 512 -> 511
        Ol[2 * x + 1] = v1.u;
    }
}

// ---------------------------------------------------------------------------
// Bilinear addressing into the y-paired copies.
__device__ __forceinline__ void addrEO(const uint4* __restrict__ E,
                                       const uint4* __restrict__ O,
                                       float gx, float gy,
                                       const uint4** p0, int* dx,
                                       float* wx, float* wy)
{
    float xs = fminf(fmaxf((gx + 1.0f) * 0.5f * 511.0f, 0.0f), 511.0f);
    float ys = fminf(fmaxf((gy + 1.0f) * 0.5f * 511.0f, 0.0f), 511.0f);
    const float x0f = floorf(xs);
    const float y0f = floorf(ys);
    *wx = xs - x0f;
    *wy = ys - y0f;
    const int x0 = (int)x0f;
    const int y0 = (int)y0f;
    const uint4* base = (y0 & 1) ? O : E;
    *p0 = base + (((size_t)(y0 >> 1)) << 9) + x0;
    *dx = (x0 < HW - 1) ? 1 : 0;                    // border clamp in x
}

// c0 = column x0: {v00 (h[0..1]), v10 (h[2..3])}; c1 = column x1: {v01, v11}.
__device__ __forceinline__ float4 blendEO(Q c0, Q c1, float wx, float wy)
{
    const float w00 = (1.0f - wx) * (1.0f - wy);
    const float w01 = wx * (1.0f - wy);
    const float w10 = (1.0f - wx) * wy;
    const float w11 = wx * wy;
    float4 o;
    o.x = w00 * __low2float (c0.h[0]) + w01 * __low2float (c1.h[0])
        + w10 * __low2float (c0.h[2]) + w11 * __low2float (c1.h[2]);
    o.y = w00 * __high2float(c0.h[0]) + w01 * __high2float(c1.h[0])
        + w10 * __high2float(c0.h[2]) + w11 * __high2float(c1.h[2]);
    o.z = w00 * __low2float (c0.h[1]) + w01 * __low2float (c1.h[1])
        + w10 * __low2float (c0.h[3]) + w11 * __low2float (c1.h[3]);
    o.w = w00 * __high2float(c0.h[1]) + w01 * __high2float(c1.h[1])
        + w10 * __high2float(c0.h[3]) + w11 * __high2float(c1.h[3]);
    return o;
}

// Pass 2 (UNCHANGED from R7 — control): 2 rows/block, thread owns pixel-pairs
// l and l+128 of its row; slab-swizzled to XCDs in REVERSE order.
__global__ __launch_bounds__(256) void spatial_transform_fp16(
    const uint4* __restrict__ E,
    const uint4* __restrict__ O,
    const fvec4* __restrict__ flow4, // [B*H*W/2]: (fh0,fw0,fh1,fw1)
    fvec4* __restrict__ grid4,       // [B*H*W/2]: (gx0,gy0,gx1,gy1)
    float* __restrict__ warped)      // [B,C,H,W]
{
    const int j    = blockIdx.x;                    // 0..4095
    const int xcd  = j & 7;
    const int i    = (j >> 3) ^ 511;                // REVERSED intra-XCD order
    const int slab = ((i >> 7) << 3) | xcd;         // 0..31
    const int rp   = (slab << 7) | (i & 127);       // row-pair 0..4095
    const int r    = (rp << 1) | ((int)threadIdx.x >> 7);  // global row
    const int l    = (int)threadIdx.x & 127;
    const int b    = r >> 9;
    const int y    = r & (HW - 1);

    const int rowq = r << 8;                        // first pair-idx of row
    const fvec4 fA = __builtin_nontemporal_load(flow4 + rowq + l);
    const fvec4 fB = __builtin_nontemporal_load(flow4 + rowq + l + 128);

    const float scale = 2.0f / 511.0f;
    const float by = fmaf((float)y, scale, -1.0f);
    const int  xA = l << 1;                         // pixels xA, xA+1
    const int  xB = xA + 256;                       // pixels xB, xB+1
    const float gyA0 = by + fA.x;
    const float gxA0 = fmaf((float)(xA + 0), scale, -1.0f) + fA.y;
    const float gyA1 = by + fA.z;
    const float gxA1 = fmaf((float)(xA + 1), scale, -1.0f) + fA.w;
    const float gyB0 = by + fB.x;
    const float gxB0 = fmaf((float)(xB + 0), scale, -1.0f) + fB.y;
    const float gyB1 = by + fB.z;
    const float gxB1 = fmaf((float)(xB + 1), scale, -1.0f) + fB.w;

    const uint4* Eb = E + ((size_t)b << 17);        // 256*512 entries/image
    const uint4* Ob = O + ((size_t)b << 17);

    // Phase A: all addresses
    const uint4 *pA0, *pA1, *pB0, *pB1;
    int dA0, dA1, dB0, dB1;
    float wxA0, wyA0, wxA1, wyA1, wxB0, wyB0, wxB1, wyB1;
    addrEO(Eb, Ob, gxA0, gyA0, &pA0, &dA0, &wxA0, &wyA0);
    addrEO(Eb, Ob, gxA1, gyA1, &pA1, &dA1, &wxA1, &wyA1);
    addrEO(Eb, Ob, gxB0, gyB0, &pB0, &dB0, &wxB0, &wyB0);
    addrEO(Eb, Ob, gxB1, gyB1, &pB1, &dB1, &wxB1, &wyB1);

    // Phase B: 8 independent gathers in flight (pairs mostly share lines)
    Q a00, a01, a10, a11, b00, b01, b10, b11;
    a00.u = pA0[0]; a01.u = pA0[dA0];
    a10.u = pA1[0]; a11.u = pA1[dA1];
    b00.u = pB0[0]; b01.u = pB0[dB0];
    b10.u = pB1[0]; b11.u = pB1[dB1];

    // grid: nt + lane-contiguous (16B/lane, no amplification, no L2 pollution)
    fvec4 gA; gA.x = gxA0; gA.y = gyA0; gA.z = gxA1; gA.w = gyA1;
    fvec4 gB; gB.x = gxB0; gB.y = gyB0; gB.z = gxB1; gB.w = gyB1;
    __builtin_nontemporal_store(gA, grid4 + rowq + l);
    __builtin_nontemporal_store(gB, grid4 + rowq + l + 128);

    // Phase C: blend + transposed channel stores (8B/lane, lane-contiguous)
    const float4 s0 = blendEO(a00, a01, wxA0, wyA0);   // pixel xA
    const float4 s1 = blendEO(a10, a11, wxA1, wyA1);   // pixel xA+1
    const float4 s2 = blendEO(b00, b01, wxB0, wyB0);   // pixel xB
    const float4 s3 = blendEO(b10, b11, wxB1, wyB1);   // pixel xB+1

    fvec2* w2 = (fvec2*)(warped + (size_t)b * CH * HWHW + y * HW);
    fvec2 o0a; o0a.x = s0.x; o0a.y = s1.x;
    fvec2 o0b; o0b.x = s2.x; o0b.y = s3.x;
    fvec2 o1a; o1a.x = s0.y; o1a.y = s1.y;
    fvec2 o1b; o1b.x = s2.y; o1b.y = s3.y;
    fvec2 o2a; o2a.x = s0.z; o2a.y = s1.z;
    fvec2 o2b; o2b.x = s2.z; o2b.y = s3.z;
    fvec2 o3a; o3a.x = s0.w; o3a.y = s1.w;
    fvec2 o3b; o3b.x = s2.w; o3b.y = s3.w;
    __builtin_nontemporal_store(o0a, w2 + 0 * (HWHW / 2) + l);
    __builtin_nontemporal_store(o0b, w2 + 0 * (HWHW / 2) + l + 128);
    __builtin_nontemporal_store(o1a, w2 + 1 * (HWHW / 2) + l);
    __builtin_nontemporal_store(o1b, w2 + 1 * (HWHW / 2) + l + 128);
    __builtin_nontemporal_store(o2a, w2 + 2 * (HWHW / 2) + l);
    __builtin_nontemporal_store(o2b, w2 + 2 * (HWHW / 2) + l + 128);
    __builtin_nontemporal_store(o3a, w2 + 3 * (HWHW / 2) + l);
    __builtin_nontemporal_store(o3b, w2 + 3 * (HWHW / 2) + l + 128);
}

// ---------------------------------------------------------------------------
// Fallback (R0 path) if workspace is too small.
__global__ __launch_bounds__(256) void spatial_transform_chw(
    const float*  __restrict__ img,
    const float2* __restrict__ flow,
    float2*       __restrict__ grid_out,
    float*        __restrict__ warped)
{
    const int tid = blockIdx.x * blockDim.x + threadIdx.x;
    const int x = tid & (HW - 1);
    const int y = (tid >> 9) & (HW - 1);
    const int b = tid >> 18;

    const float2 f = flow[tid];
    const float scale = 2.0f / 511.0f;
    const float gy = fmaf((float)y, scale, -1.0f) + f.x;
    const float gx = fmaf((float)x, scale, -1.0f) + f.y;
    grid_out[tid] = make_float2(gx, gy);

    float xs = fminf(fmaxf((gx + 1.0f) * 0.5f * 511.0f, 0.0f), 511.0f);
    float ys = fminf(fmaxf((gy + 1.0f) * 0.5f * 511.0f, 0.0f), 511.0f);
    const float x0f = floorf(xs), y0f = floorf(ys);
    const float wx = xs - x0f, wy = ys - y0f;
    const int x0 = (int)x0f, y0 = (int)y0f;
    const int x1 = min(x0 + 1, HW - 1), y1 = min(y0 + 1, HW - 1);
    const float w00 = (1.0f - wx) * (1.0f - wy), w01 = wx * (1.0f - wy);
    const float w10 = (1.0f - wx) * wy,          w11 = wx * wy;
    const int o00 = y0 * HW + x0, o01 = y0 * HW + x1;
    const int o10 = y1 * HW + x0, o11 = y1 * HW + x1;
    const float* ib = img    + (size_t)b * CH * HWHW;
    float*       wb = warped + (size_t)b * CH * HWHW + y * HW + x;
#pragma unroll
    for (int c = 0; c < CH; ++c) {
        const float* pc = ib + c * HWHW;
        wb[c * HWHW] = pc[o00] * w00 + pc[o01] * w01 + pc[o10] * w10 + pc[o11] * w11;
    }
}

extern "C" void kernel_launch(void* const* d_in, const int* in_sizes, int n_in,
                              void* d_out, int out_size, void* d_ws, size_t ws_size,
                              hipStream_t stream) {
    const float* img  = (const float*)d_in[0];
    const void*  flow = d_in[1];

    float* grid_out = (float*)d_out;                                  // B*H*W*2 floats
    float* warped   = (float*)d_out + (size_t)BATCH * HWHW * 2;       // B*C*H*W floats

    const int n_px = BATCH * HWHW;                       // 4,194,304 pixels
    const size_t copy_bytes = (size_t)n_px * 8;          // 32 MiB per copy
    const size_t need = 2 * copy_bytes;                  // 64 MiB (E + O)

    if (ws_size >= need) {
        uint4* Ec = (uint4*)d_ws;
        uint4* Oc = (uint4*)((char*)d_ws + copy_bytes);
        transpose_fp16_pair<<<BATCH * 256, 512, 0, stream>>>(
            img, Ec, Oc);
        spatial_transform_fp16<<<(n_px / 4) / 256, 256, 0, stream>>>(
            (const uint4*)Ec, (const uint4*)Oc,
            (const fvec4*)flow, (fvec4*)grid_out, warped);
    } else {
        spatial_transform_chw<<<n_px / 256, 256, 0, stream>>>(
            img, (const float2*)flow, (float2*)grid_out, warped);
    }
}